// Round 2
// baseline (262.971 us; speedup 1.0000x reference)
//
#include <hip/hip_runtime.h>
#include <math.h>

#define NUM_CLASSES 722
#define NROWS 65536            // 16 * 4096
#define F2_PER_ROW 361         // 722 floats = 361 float2 (8B-aligned per row)
#define ROWS_PER_BLOCK 4
#define GRID1 (NROWS / ROWS_PER_BLOCK)   // 16384

// exp(-2^d / 4) for d = 1,2,3 ; d=0 slot is overwritten by the final 1.0 scatter
#define W1 0.60653065971263342f   // exp(-0.5)
#define W2 0.36787944117144233f   // exp(-1)
#define W3 0.13533528323661270f   // exp(-2)

__global__ __launch_bounds__(256) void ce_rows_kernel(
    const float* __restrict__ pred,
    const int*   __restrict__ target,
    float*       __restrict__ block_sums)
{
    const int wave = threadIdx.x >> 6;
    const int lane = threadIdx.x & 63;
    const int row  = blockIdx.x * ROWS_PER_BLOCK + wave;

    const float2* rowp = reinterpret_cast<const float2*>(pred) + (size_t)row * F2_PER_ROW;

    // ---- load row into registers (coalesced float2), track max ----
    float2 v[6];
    float m = -INFINITY;
#pragma unroll
    for (int k = 0; k < 6; ++k) {
        int idx = lane + k * 64;
        v[k] = make_float2(0.f, 0.f);
        if (idx < F2_PER_ROW) {
            v[k] = rowp[idx];
            m = fmaxf(m, fmaxf(v[k].x, v[k].y));
        }
    }
    // wave-reduce max (64 lanes)
#pragma unroll
    for (int off = 32; off >= 1; off >>= 1)
        m = fmaxf(m, __shfl_xor(m, off, 64));

    // ---- smoothed-label parameters for this row ----
    const int t  = target[row];
    const int p1 = min(t + 1, NUM_CLASSES - 1), q1 = max(t - 1, 0);
    const int p2 = min(t + 2, NUM_CLASSES - 1), q2 = max(t - 2, 0);
    const int p3 = min(t + 3, NUM_CLASSES - 1), q3 = max(t - 3, 0);

    // ---- second register pass: sum exp, weighted dot, weight sum ----
    float s = 0.f, dot = 0.f, wsum = 0.f;
#pragma unroll
    for (int k = 0; k < 6; ++k) {
        int idx = lane + k * 64;
        if (idx < F2_PER_ROW) {
            int c0 = idx * 2, c1 = c0 + 1;
            s += __expf(v[k].x - m) + __expf(v[k].y - m);
            // reverse-write-order priority: t(1.0), t±1, t±2, t±3 (clipped)
            float w0 = (c0 == t)  ? 1.0f :
                       (c0 == p1) ? W1 : (c0 == q1) ? W1 :
                       (c0 == p2) ? W2 : (c0 == q2) ? W2 :
                       (c0 == p3) ? W3 : (c0 == q3) ? W3 : 0.0f;
            float w1 = (c1 == t)  ? 1.0f :
                       (c1 == p1) ? W1 : (c1 == q1) ? W1 :
                       (c1 == p2) ? W2 : (c1 == q2) ? W2 :
                       (c1 == p3) ? W3 : (c1 == q3) ? W3 : 0.0f;
            dot  += w0 * v[k].x + w1 * v[k].y;
            wsum += w0 + w1;
        }
    }
#pragma unroll
    for (int off = 32; off >= 1; off >>= 1) {
        s    += __shfl_xor(s,    off, 64);
        dot  += __shfl_xor(dot,  off, 64);
        wsum += __shfl_xor(wsum, off, 64);
    }

    __shared__ float lds[ROWS_PER_BLOCK];
    if (lane == 0) {
        float lse = m + __logf(s);
        lds[wave] = lse * wsum - dot;   // row loss
    }
    __syncthreads();
    if (threadIdx.x == 0)
        block_sums[blockIdx.x] = lds[0] + lds[1] + lds[2] + lds[3];
}

__global__ __launch_bounds__(1024) void reduce_final_kernel(
    const float* __restrict__ block_sums,
    float*       __restrict__ out,
    int n)
{
    float s = 0.f;
    for (int i = threadIdx.x; i < n; i += 1024)
        s += block_sums[i];
#pragma unroll
    for (int off = 32; off >= 1; off >>= 1)
        s += __shfl_xor(s, off, 64);

    __shared__ float lds[16];
    const int wave = threadIdx.x >> 6, lane = threadIdx.x & 63;
    if (lane == 0) lds[wave] = s;
    __syncthreads();
    if (threadIdx.x == 0) {
        float tot = 0.f;
#pragma unroll
        for (int i = 0; i < 16; ++i) tot += lds[i];
        out[0] = tot * (1.0f / (float)NROWS);
    }
}

extern "C" void kernel_launch(void* const* d_in, const int* in_sizes, int n_in,
                              void* d_out, int out_size, void* d_ws, size_t ws_size,
                              hipStream_t stream)
{
    const float* pred   = (const float*)d_in[0];
    const int*   target = (const int*)d_in[1];
    float* out        = (float*)d_out;
    float* block_sums = (float*)d_ws;   // GRID1 * 4 = 64 KB scratch

    ce_rows_kernel<<<GRID1, 256, 0, stream>>>(pred, target, block_sums);
    reduce_final_kernel<<<1, 1024, 0, stream>>>(block_sums, out, GRID1);
}

// Round 4
// 257.222 us; speedup vs baseline: 1.0224x; 1.0224x over previous
//
#include <hip/hip_runtime.h>
#include <math.h>

#define NUM_CLASSES 722
#define NROWS 65536            // 16 * 4096
#define ROWS_PER_BLOCK 4
#define GRID1 (NROWS / ROWS_PER_BLOCK)   // 16384

// exp(-2^d / 4) for d = 1,2,3 ; d=0 slot is overwritten by the final 1.0 scatter
#define W1 0.60653065971263342f   // exp(-0.5)
#define W2 0.36787944117144233f   // exp(-1)
#define W3 0.13533528323661270f   // exp(-2)

__global__ __launch_bounds__(256) void ce_rows_kernel(
    const float* __restrict__ pred,
    const int*   __restrict__ target,
    float*       __restrict__ block_sums)
{
    const int wave = threadIdx.x >> 6;
    const int lane = threadIdx.x & 63;
    const int row  = blockIdx.x * ROWS_PER_BLOCK + wave;

    const float* base = pred + (size_t)row * NUM_CLASSES;

    // ---- smoothed-label dot via direct gather (wave-uniform addresses) ----
    // Priority order = reverse scatter-write order: t (1.0) wins, then t±1,
    // t±2, t±3 clipped. Dedup reproduces last-write-wins at the boundaries.
    const int t  = target[row];
    const int c0 = t;
    const int c1 = min(t + 1, NUM_CLASSES - 1), c2 = max(t - 1, 0);
    const int c3 = min(t + 2, NUM_CLASSES - 1), c4 = max(t - 2, 0);
    const int c5 = min(t + 3, NUM_CLASSES - 1), c6 = max(t - 3, 0);
    const float g0 = base[c0], g1 = base[c1], g2 = base[c2], g3 = base[c3],
                g4 = base[c4], g5 = base[c5], g6 = base[c6];

    // ---- streaming load: 180 float4 + 1 float2, alignment by row parity ----
    // Row stride = 2888 B: even rows 16B-aligned (tail float2 at elem 720),
    // odd rows base%16==8 (head float2 at elem 0, float4s from elem 2).
    const int p = row & 1;
    const float4* v4 = reinterpret_cast<const float4*>(base + 2 * p);
    const float NEG_INF = -INFINITY;

    float4 v[3];
    v[0] = v4[lane];
    v[1] = v4[lane + 64];
    v[2] = make_float4(NEG_INF, NEG_INF, NEG_INF, NEG_INF);
    if (lane < 52) v[2] = v4[lane + 128];          // 180 = 2*64 + 52
    float2 ex = make_float2(NEG_INF, NEG_INF);
    if (lane == 63) ex = reinterpret_cast<const float2*>(base)[p ? 0 : 360];

    // ---- max ----
    float m = fmaxf(fmaxf(fmaxf(v[0].x, v[0].y), fmaxf(v[0].z, v[0].w)),
                    fmaxf(fmaxf(v[1].x, v[1].y), fmaxf(v[1].z, v[1].w)));
    m = fmaxf(m, fmaxf(fmaxf(v[2].x, v[2].y), fmaxf(v[2].z, v[2].w)));
    m = fmaxf(m, fmaxf(ex.x, ex.y));
#pragma unroll
    for (int off = 32; off >= 1; off >>= 1)
        m = fmaxf(m, __shfl_xor(m, off, 64));

    // ---- sum of exp (inactive slots are -inf -> exp == 0) ----
    float s = __expf(v[0].x - m) + __expf(v[0].y - m)
            + __expf(v[0].z - m) + __expf(v[0].w - m)
            + __expf(v[1].x - m) + __expf(v[1].y - m)
            + __expf(v[1].z - m) + __expf(v[1].w - m)
            + __expf(v[2].x - m) + __expf(v[2].y - m)
            + __expf(v[2].z - m) + __expf(v[2].w - m)
            + __expf(ex.x - m)   + __expf(ex.y - m);
#pragma unroll
    for (int off = 32; off >= 1; off >>= 1)
        s += __shfl_xor(s, off, 64);

    // ---- weighted dot with priority dedup (uniform scalar work) ----
    float dot = g0, wsum = 1.0f;
    if (c1 != c0) { dot += W1 * g1; wsum += W1; }
    if (c2 != c0 && c2 != c1) { dot += W1 * g2; wsum += W1; }
    if (c3 != c0 && c3 != c1 && c3 != c2) { dot += W2 * g3; wsum += W2; }
    if (c4 != c0 && c4 != c1 && c4 != c2 && c4 != c3) { dot += W2 * g4; wsum += W2; }
    if (c5 != c0 && c5 != c1 && c5 != c2 && c5 != c3 && c5 != c4) { dot += W3 * g5; wsum += W3; }
    if (c6 != c0 && c6 != c1 && c6 != c2 && c6 != c3 && c6 != c4 && c6 != c5) { dot += W3 * g6; wsum += W3; }

    __shared__ float lds[ROWS_PER_BLOCK];
    if (lane == 0) {
        float lse = m + __logf(s);
        lds[wave] = lse * wsum - dot;   // row loss
    }
    __syncthreads();
    if (threadIdx.x == 0)
        block_sums[blockIdx.x] = lds[0] + lds[1] + lds[2] + lds[3];
}

__global__ __launch_bounds__(1024) void reduce_final_kernel(
    const float* __restrict__ block_sums,
    float*       __restrict__ out,
    int n)
{
    float s = 0.f;
    for (int i = threadIdx.x; i < n; i += 1024)
        s += block_sums[i];
#pragma unroll
    for (int off = 32; off >= 1; off >>= 1)
        s += __shfl_xor(s, off, 64);

    __shared__ float lds[16];
    const int wave = threadIdx.x >> 6, lane = threadIdx.x & 63;
    if (lane == 0) lds[wave] = s;
    __syncthreads();
    if (threadIdx.x == 0) {
        float tot = 0.f;
#pragma unroll
        for (int i = 0; i < 16; ++i) tot += lds[i];
        out[0] = tot * (1.0f / (float)NROWS);
    }
}

extern "C" void kernel_launch(void* const* d_in, const int* in_sizes, int n_in,
                              void* d_out, int out_size, void* d_ws, size_t ws_size,
                              hipStream_t stream)
{
    const float* pred   = (const float*)d_in[0];
    const int*   target = (const int*)d_in[1];
    float* out        = (float*)d_out;
    float* block_sums = (float*)d_ws;   // GRID1 * 4 = 64 KB scratch

    ce_rows_kernel<<<GRID1, 256, 0, stream>>>(pred, target, block_sums);
    reduce_final_kernel<<<1, 1024, 0, stream>>>(block_sums, out, GRID1);
}